// Round 5
// baseline (253.430 us; speedup 1.0000x reference)
//
#include <hip/hip_runtime.h>
#include <math.h>

#define S_DIM 2048
#define B_DIM 128
#define P_DIM 1024   // sized for sep <= 1024 (actual sep read from device)
#define E_DIM 192
#define SB    (S_DIM * B_DIM)

typedef float f32x4 __attribute__((ext_vector_type(4)));
typedef float f32x2 __attribute__((ext_vector_type(2)));

// ---------------------------------------------------------------------------
// Kernel 1: per-column prep + rank. One block per column b (128 blocks, 256t).
//   - load prefix y[0:sep, b] into LDS (pad to 1024 with +INF)
//   - nanmean reduce -> mean (register, all threads)
//   - impute NaN/Inf -> mean in LDS
//   - bitonic sort 1024 elements in LDS
//   - dedupe via block scan -> unique values su[0..K) in LDS
//   - for all s: indicator + imputed value + binary-search rank -> ri[b*S+s]
// ---------------------------------------------------------------------------
__global__ __launch_bounds__(256) void prep_rank_kernel(
    const float* __restrict__ y, const int* __restrict__ sep_p,
    f32x2* __restrict__ ri) {
  __shared__ float sm[P_DIM];
  __shared__ float su[P_DIM];
  __shared__ float redf[256];
  __shared__ int   redi[256];
  __shared__ int   scan[256];
  __shared__ int   Ksh;

  const int b   = blockIdx.x;
  const int tid = threadIdx.x;
  const int sep = *sep_p;

  // Load prefix column + nan-aware sum
  float lsum = 0.f;
  int   lcnt = 0;
  for (int i = tid; i < P_DIM; i += 256) {
    float v = (i < sep) ? y[i * B_DIM + b] : INFINITY;
    sm[i] = v;
    if (i < sep && !isnan(v)) { lsum += v; lcnt++; }
  }
  redf[tid] = lsum;
  redi[tid] = lcnt;
  __syncthreads();
  for (int off = 128; off > 0; off >>= 1) {
    if (tid < off) { redf[tid] += redf[tid + off]; redi[tid] += redi[tid + off]; }
    __syncthreads();
  }
  const float mean = redf[0] / (float)redi[0];

  // Impute NaN/Inf -> mean (same thread owns these slots; mean valid post-barrier)
  for (int i = tid; i < sep; i += 256) {
    float v = sm[i];
    if (isnan(v) || isinf(v)) sm[i] = mean;
  }
  __syncthreads();

  // Bitonic sort of 1024 elements with 256 threads
  for (int k = 2; k <= P_DIM; k <<= 1) {
    for (int j = k >> 1; j > 0; j >>= 1) {
      for (int i = tid; i < P_DIM; i += 256) {
        int ixj = i ^ j;
        if (ixj > i) {
          float a = sm[i], c = sm[ixj];
          bool up = ((i & k) == 0);
          if (up ? (a > c) : (a < c)) { sm[i] = c; sm[ixj] = a; }
        }
      }
      __syncthreads();
    }
  }

  // Dedupe: new-value flags + block scan; unique values -> su (LDS)
  int flags[4];
  int lu = 0;
  for (int q = 0; q < 4; q++) {
    int i = tid * 4 + q;
    bool nw = (i == 0) || (sm[i] != sm[i - 1]);
    flags[q] = nw ? 1 : 0;
    lu += flags[q];
  }
  scan[tid] = lu;
  __syncthreads();
  for (int off = 1; off < 256; off <<= 1) {
    int t = (tid >= off) ? scan[tid - off] : 0;
    __syncthreads();
    scan[tid] += t;
    __syncthreads();
  }
  int excl = scan[tid] - lu;
  for (int q = 0; q < 4; q++) {
    int i = tid * 4 + q;
    if (flags[q]) { su[excl] = sm[i]; excl++; }
  }
  if (tid == 255) Ksh = scan[255];
  __syncthreads();

  const int K = Ksh;

  // Rank phase: all S rows of this column (8 iterations/thread)
  for (int s = tid; s < S_DIM; s += 256) {
    const float v = y[s * B_DIM + b];
    float ind = 0.f;
    float x = v;
    if (isnan(v))      { ind = -2.f; x = mean; }
    else if (isinf(v)) { ind = (v > 0.f) ? 2.f : 4.f; x = mean; }
    int lo = 0, hi = K;
    while (lo < hi) {
      int mid = (lo + hi) >> 1;
      if (su[mid] < x) lo = mid + 1; else hi = mid;
    }
    f32x2 rv; rv.x = (float)lo; rv.y = ind;
    ri[b * S_DIM + s] = rv;
  }
}

// ---------------------------------------------------------------------------
// Kernel 2: streaming broadcast write (192 MiB).
// Fixed-q mapping: thread owns output quad q forever -> W/bias in registers.
// out[sb*48 + q] = rank*W[.,0] + ind*W[.,1] + bias, nontemporal f32x4 store.
// ---------------------------------------------------------------------------
__global__ __launch_bounds__(192) void out_kernel(
    const f32x2* __restrict__ ri, const f32x4* __restrict__ Wf,
    const f32x4* __restrict__ bias4, f32x4* __restrict__ out) {
  const int q  = threadIdx.x % 48;          // which float4 of the 48-per-row
  const int r0 = threadIdx.x / 48;          // which of 4 rows this block-iter
  const f32x4 wa = Wf[2 * q];               // {W[4q,0],W[4q,1],W[4q+1,0],W[4q+1,1]}
  const f32x4 wb = Wf[2 * q + 1];
  const f32x4 bb = bias4[q];
  const int stride = gridDim.x * 4;
  for (int sb = blockIdx.x * 4 + r0; sb < SB; sb += stride) {
    const int s = sb >> 7;                  // / B_DIM
    const int b = sb & (B_DIM - 1);
    const f32x2 rv = ri[b * S_DIM + s];
    f32x4 o;
    o.x = fmaf(rv.x, wa.x, fmaf(rv.y, wa.y, bb.x));
    o.y = fmaf(rv.x, wa.z, fmaf(rv.y, wa.w, bb.y));
    o.z = fmaf(rv.x, wb.x, fmaf(rv.y, wb.y, bb.z));
    o.w = fmaf(rv.x, wb.z, fmaf(rv.y, wb.w, bb.w));
    __builtin_nontemporal_store(o, &out[(size_t)sb * 48 + q]);
  }
}

extern "C" void kernel_launch(void* const* d_in, const int* in_sizes, int n_in,
                              void* d_out, int out_size, void* d_ws, size_t ws_size,
                              hipStream_t stream) {
  const float* y    = (const float*)d_in[0];
  const float* W    = (const float*)d_in[1];
  const float* bias = (const float*)d_in[2];
  const int*   sep  = (const int*)d_in[3];

  // Workspace: ri : f32x2[S*B]  (2 MiB)
  f32x2* ri = (f32x2*)d_ws;

  prep_rank_kernel<<<B_DIM, 256, 0, stream>>>(y, sep, ri);

  out_kernel<<<4096, 192, 0, stream>>>(ri, (const f32x4*)W,
                                       (const f32x4*)bias, (f32x4*)d_out);
}

// Round 7
// 222.060 us; speedup vs baseline: 1.1413x; 1.1413x over previous
//
#include <hip/hip_runtime.h>
#include <math.h>

#define S_DIM 2048
#define B_DIM 128
#define P_DIM 1024   // sized for sep <= 1024 (actual sep read from device)
#define E_DIM 192
#define SB    (S_DIM * B_DIM)

typedef float f32x4 __attribute__((ext_vector_type(4)));
typedef float f32x2 __attribute__((ext_vector_type(2)));

// ---------------------------------------------------------------------------
// Kernel 1: per-column prep + rank. One block per column b (128 blocks,
// 1024 threads, 1 element per thread).
//   - load y[tid, b] (pad +INF), nanmean via shfl-reduce + 16 partials
//   - impute NaN/Inf -> mean (in register)
//   - bitonic sort: j<64 via __shfl_xor (no barrier, 45 stages),
//                   j>=64 via LDS (10 stages, 2 barriers each)
//   - dedupe via __ballot + popcll wave scan + 16-partial block scan
//   - rank: 2 binary searches per thread -> ri[b*S+s]
// ---------------------------------------------------------------------------
__global__ __launch_bounds__(1024) void prep_rank_kernel(
    const float* __restrict__ y, const int* __restrict__ sep_p,
    f32x2* __restrict__ ri) {
  __shared__ float sm[P_DIM];
  __shared__ float su[P_DIM];
  __shared__ float wred[16];
  __shared__ int   wredi[16];
  __shared__ int   wbase[16];
  __shared__ int   Ksh;
  __shared__ float meansh;

  const int tid  = threadIdx.x;
  const int lane = tid & 63;
  const int w    = tid >> 6;            // wave id 0..15
  const int b    = blockIdx.x;
  const int sep  = *sep_p;

  // ---- load + nan-aware sum (infs ARE included in the mean, like nanmean) --
  float v = (tid < sep) ? y[tid * B_DIM + b] : INFINITY;
  const bool valid = (tid < sep) && !isnan(v);
  float sv = valid ? v : 0.f;
  int   ci = valid ? 1 : 0;
  for (int off = 32; off; off >>= 1) {
    sv += __shfl_down(sv, off);
    ci += __shfl_down(ci, off);
  }
  if (lane == 0) { wred[w] = sv; wredi[w] = ci; }
  __syncthreads();
  if (tid == 0) {
    float s = 0.f; int c = 0;
    for (int i = 0; i < 16; i++) { s += wred[i]; c += wredi[i]; }
    meansh = s / (float)c;
  }
  __syncthreads();
  const float mean = meansh;

  // ---- impute (register) ---------------------------------------------------
  if (tid < sep && (isnan(v) || isinf(v))) v = mean;

  // ---- bitonic sort, 1 elem/thread ----------------------------------------
  for (int k = 2; k <= P_DIM; k <<= 1) {
    for (int j = k >> 1; j; j >>= 1) {
      float pv;
      if (j >= 64) {
        sm[tid] = v;
        __syncthreads();
        pv = sm[tid ^ j];
        __syncthreads();
      } else {
        pv = __shfl_xor(v, j);
      }
      const bool up    = ((tid & k) == 0);
      const bool lower = ((tid & j) == 0);
      const float mn = fminf(v, pv), mx = fmaxf(v, pv);
      v = (up == lower) ? mn : mx;
    }
  }

  // ---- dedupe: ballot scan -------------------------------------------------
  sm[tid] = v;
  __syncthreads();
  const bool flag = (tid == 0) || (v != sm[tid - 1]);
  const unsigned long long mask = __ballot(flag);
  const int lower = __popcll(mask & ((1ull << lane) - 1ull));
  const int wcnt  = __popcll(mask);
  if (lane == 0) wbase[w] = wcnt;
  __syncthreads();
  if (tid == 0) {
    int acc = 0;
    for (int i = 0; i < 16; i++) { int t = wbase[i]; wbase[i] = acc; acc += t; }
    Ksh = acc;
  }
  __syncthreads();
  if (flag) su[wbase[w] + lower] = v;
  __syncthreads();
  const int K = Ksh;

  // ---- rank: 2 rows per thread --------------------------------------------
  for (int it = 0; it < 2; ++it) {
    const int s = it * P_DIM + tid;
    const float q = y[s * B_DIM + b];
    float ind = 0.f;
    float x = q;
    if (isnan(q))      { ind = -2.f; x = mean; }
    else if (isinf(q)) { ind = (q > 0.f) ? 2.f : 4.f; x = mean; }
    int lo = 0, hi = K;
    while (lo < hi) {
      int mid = (lo + hi) >> 1;
      if (su[mid] < x) lo = mid + 1; else hi = mid;
    }
    f32x2 rv; rv.x = (float)lo; rv.y = ind;
    ri[b * S_DIM + s] = rv;
  }
}

// ---------------------------------------------------------------------------
// Kernel 2: streaming broadcast write (192 MiB).
// Fixed-q mapping: thread owns output quad q forever -> W/bias in registers.
// out[sb*48 + q] = rank*W[.,0] + ind*W[.,1] + bias, nontemporal f32x4 store.
// ---------------------------------------------------------------------------
__global__ __launch_bounds__(192) void out_kernel(
    const f32x2* __restrict__ ri, const f32x4* __restrict__ Wf,
    const f32x4* __restrict__ bias4, f32x4* __restrict__ out) {
  const int q  = threadIdx.x % 48;          // which float4 of the 48-per-row
  const int r0 = threadIdx.x / 48;          // which of 4 rows this block-iter
  const f32x4 wa = Wf[2 * q];               // {W[4q,0],W[4q,1],W[4q+1,0],W[4q+1,1]}
  const f32x4 wb = Wf[2 * q + 1];
  const f32x4 bb = bias4[q];
  const int stride = gridDim.x * 4;
  for (int sb = blockIdx.x * 4 + r0; sb < SB; sb += stride) {
    const int s = sb >> 7;                  // / B_DIM
    const int b = sb & (B_DIM - 1);
    const f32x2 rv = ri[b * S_DIM + s];
    f32x4 o;
    o.x = fmaf(rv.x, wa.x, fmaf(rv.y, wa.y, bb.x));
    o.y = fmaf(rv.x, wa.z, fmaf(rv.y, wa.w, bb.y));
    o.z = fmaf(rv.x, wb.x, fmaf(rv.y, wb.y, bb.z));
    o.w = fmaf(rv.x, wb.z, fmaf(rv.y, wb.w, bb.w));
    __builtin_nontemporal_store(o, &out[(size_t)sb * 48 + q]);
  }
}

extern "C" void kernel_launch(void* const* d_in, const int* in_sizes, int n_in,
                              void* d_out, int out_size, void* d_ws, size_t ws_size,
                              hipStream_t stream) {
  const float* y    = (const float*)d_in[0];
  const float* W    = (const float*)d_in[1];
  const float* bias = (const float*)d_in[2];
  const int*   sep  = (const int*)d_in[3];

  // Workspace: ri : f32x2[S*B]  (2 MiB)
  f32x2* ri = (f32x2*)d_ws;

  prep_rank_kernel<<<B_DIM, 1024, 0, stream>>>(y, sep, ri);

  out_kernel<<<4096, 192, 0, stream>>>(ri, (const f32x4*)W,
                                       (const f32x4*)bias, (f32x4*)d_out);
}

// Round 10
// 216.385 us; speedup vs baseline: 1.1712x; 1.0262x over previous
//
#include <hip/hip_runtime.h>
#include <math.h>

#define S_DIM 2048
#define B_DIM 128
#define P_DIM 1024   // sized for sep <= 1024 (actual sep read from device)
#define E_DIM 192
#define SB    (S_DIM * B_DIM)

typedef float f32x4 __attribute__((ext_vector_type(4)));
typedef float f32x2 __attribute__((ext_vector_type(2)));

// ---------------------------------------------------------------------------
// Kernel 1: per-column prep + rank. One block per column b (128 blocks,
// 1024 threads, 1 element per thread). Identical to round-7 version.
// ---------------------------------------------------------------------------
__global__ __launch_bounds__(1024) void prep_rank_kernel(
    const float* __restrict__ y, const int* __restrict__ sep_p,
    f32x2* __restrict__ ri) {
  __shared__ float sm[P_DIM];
  __shared__ float su[P_DIM];
  __shared__ float wred[16];
  __shared__ int   wredi[16];
  __shared__ int   wbase[16];
  __shared__ int   Ksh;
  __shared__ float meansh;

  const int tid  = threadIdx.x;
  const int lane = tid & 63;
  const int w    = tid >> 6;            // wave id 0..15
  const int b    = blockIdx.x;
  const int sep  = *sep_p;

  // ---- load + nan-aware sum (infs ARE included in the mean, like nanmean) --
  float v = (tid < sep) ? y[tid * B_DIM + b] : INFINITY;
  const bool valid = (tid < sep) && !isnan(v);
  float sv = valid ? v : 0.f;
  int   ci = valid ? 1 : 0;
  for (int off = 32; off; off >>= 1) {
    sv += __shfl_down(sv, off);
    ci += __shfl_down(ci, off);
  }
  if (lane == 0) { wred[w] = sv; wredi[w] = ci; }
  __syncthreads();
  if (tid == 0) {
    float s = 0.f; int c = 0;
    for (int i = 0; i < 16; i++) { s += wred[i]; c += wredi[i]; }
    meansh = s / (float)c;
  }
  __syncthreads();
  const float mean = meansh;

  // ---- impute (register) ---------------------------------------------------
  if (tid < sep && (isnan(v) || isinf(v))) v = mean;

  // ---- bitonic sort, 1 elem/thread ----------------------------------------
  for (int k = 2; k <= P_DIM; k <<= 1) {
    for (int j = k >> 1; j; j >>= 1) {
      float pv;
      if (j >= 64) {
        sm[tid] = v;
        __syncthreads();
        pv = sm[tid ^ j];
        __syncthreads();
      } else {
        pv = __shfl_xor(v, j);
      }
      const bool up    = ((tid & k) == 0);
      const bool lower = ((tid & j) == 0);
      const float mn = fminf(v, pv), mx = fmaxf(v, pv);
      v = (up == lower) ? mn : mx;
    }
  }

  // ---- dedupe: ballot scan -------------------------------------------------
  sm[tid] = v;
  __syncthreads();
  const bool flag = (tid == 0) || (v != sm[tid - 1]);
  const unsigned long long mask = __ballot(flag);
  const int lower = __popcll(mask & ((1ull << lane) - 1ull));
  const int wcnt  = __popcll(mask);
  if (lane == 0) wbase[w] = wcnt;
  __syncthreads();
  if (tid == 0) {
    int acc = 0;
    for (int i = 0; i < 16; i++) { int t = wbase[i]; wbase[i] = acc; acc += t; }
    Ksh = acc;
  }
  __syncthreads();
  if (flag) su[wbase[w] + lower] = v;
  __syncthreads();
  const int K = Ksh;

  // ---- rank: 2 rows per thread --------------------------------------------
  for (int it = 0; it < 2; ++it) {
    const int s = it * P_DIM + tid;
    const float q = y[s * B_DIM + b];
    float ind = 0.f;
    float x = q;
    if (isnan(q))      { ind = -2.f; x = mean; }
    else if (isinf(q)) { ind = (q > 0.f) ? 2.f : 4.f; x = mean; }
    int lo = 0, hi = K;
    while (lo < hi) {
      int mid = (lo + hi) >> 1;
      if (su[mid] < x) lo = mid + 1; else hi = mid;
    }
    f32x2 rv; rv.x = (float)lo; rv.y = ind;
    ri[b * S_DIM + s] = rv;
  }
}

// ---------------------------------------------------------------------------
// Kernel 2: streaming broadcast write (192 MiB), REGULAR stores (no NT).
// Fixed-q mapping; grid fixed at 4096 blocks -> 16 compile-time iterations,
// fully unrolled so the 16 independent ri loads are hoisted ahead of stores.
// Per block: b = sb0 & 127 is constant; s = (sb0>>7) + it*128.
// ---------------------------------------------------------------------------
__global__ __launch_bounds__(192) void out_kernel(
    const f32x2* __restrict__ ri, const f32x4* __restrict__ Wf,
    const f32x4* __restrict__ bias4, f32x4* __restrict__ out) {
  const int q  = threadIdx.x % 48;          // which float4 of the 48-per-row
  const int r0 = threadIdx.x / 48;          // which of 4 rows per block-iter
  const f32x4 wa = Wf[2 * q];               // {W[4q,0],W[4q,1],W[4q+1,0],W[4q+1,1]}
  const f32x4 wb = Wf[2 * q + 1];
  const f32x4 bb = bias4[q];
  const int sb0   = blockIdx.x * 4 + r0;    // in [0, 16384)
  const int b     = sb0 & (B_DIM - 1);
  const int sBase = sb0 >> 7;
  const f32x2* rcol = ri + b * S_DIM;
#pragma unroll
  for (int it = 0; it < 16; ++it) {
    const f32x2 rv = rcol[sBase + it * 128];
    f32x4 o;
    o.x = fmaf(rv.x, wa.x, fmaf(rv.y, wa.y, bb.x));
    o.y = fmaf(rv.x, wa.z, fmaf(rv.y, wa.w, bb.y));
    o.z = fmaf(rv.x, wb.x, fmaf(rv.y, wb.y, bb.z));
    o.w = fmaf(rv.x, wb.z, fmaf(rv.y, wb.w, bb.w));
    out[(size_t)(sb0 + it * 16384) * 48 + q] = o;
  }
}

extern "C" void kernel_launch(void* const* d_in, const int* in_sizes, int n_in,
                              void* d_out, int out_size, void* d_ws, size_t ws_size,
                              hipStream_t stream) {
  const float* y    = (const float*)d_in[0];
  const float* W    = (const float*)d_in[1];
  const float* bias = (const float*)d_in[2];
  const int*   sep  = (const int*)d_in[3];

  // Workspace: ri : f32x2[S*B]  (2 MiB)
  f32x2* ri = (f32x2*)d_ws;

  prep_rank_kernel<<<B_DIM, 1024, 0, stream>>>(y, sep, ri);

  out_kernel<<<4096, 192, 0, stream>>>(ri, (const f32x4*)W,
                                       (const f32x4*)bias, (f32x4*)d_out);
}